// Round 11
// baseline (121.476 us; speedup 1.0000x reference)
//
#include <hip/hip_runtime.h>
#include <hip/hip_bf16.h>
#include <float.h>

// Problem constants
constexpr int B   = 2;
constexpr int N   = 16384;
constexpr int S   = 4096;
constexpr int INC = 256;
constexpr int OUTC = 128;

// Workspace layout (bytes). R8-R10 behavior proves ws_size >= 5.21 MB
// (otherwise their R7-identical fallback would have run and passed).
constexpr size_t OFF_DOWNF = 0;                          // B*S*128*4 = 4 MB
constexpr size_t OFF_QIDX  = 4194304;                    // B*N*3*4
constexpr size_t OFF_QW    = OFF_QIDX + 393216;          // B*N*3*4
constexpr size_t WS_NEED   = OFF_QW + 393216;            // ~4.98 MB

typedef short short4_t __attribute__((ext_vector_type(4)));
typedef short short8_t __attribute__((ext_vector_type(8)));
typedef float f32x4    __attribute__((ext_vector_type(4)));

__device__ __forceinline__ unsigned short f2bf(float f) {
    unsigned u = __builtin_bit_cast(unsigned, f);
    u += 0x7fffu + ((u >> 16) & 1u);
    return (unsigned short)(u >> 16);
}

// ---------------------------------------------------------------------------
// MFMA GEMM (unchanged, passing since R6).
// ---------------------------------------------------------------------------
template <int K, int ROWS>
__global__ __launch_bounds__(256) void k_mfma(const float* __restrict__ f,
                                              const float* __restrict__ W,
                                              const float* __restrict__ bias,
                                              float* __restrict__ outf) {
    constexpr int MF = ROWS / 16;
    constexpr int KS = K / 32;
    __shared__ __align__(16) short smem[K * 128];

    const int tid  = threadIdx.x;
    const int lane = tid & 63;
    const int wv   = tid >> 6;
    const int rowbase = blockIdx.x * ROWS;
    const int lo16 = lane & 15;
    const int hi8  = (lane >> 4) * 8;

    const float4* w4 = reinterpret_cast<const float4*>(W);
    for (int n = tid; n < K * 32; n += 256) {
        const float4 u = w4[n];
        short4_t s = { (short)f2bf(u.x), (short)f2bf(u.y),
                       (short)f2bf(u.z), (short)f2bf(u.w) };
        *reinterpret_cast<short4_t*>(&smem[n * 4]) = s;
    }
    __syncthreads();

    short8_t bf[KS][2];
    #pragma unroll
    for (int ks = 0; ks < KS; ++ks) {
        #pragma unroll
        for (int c = 0; c < 2; ++c) {
            const int col = wv * 32 + c * 16 + lo16;
            #pragma unroll
            for (int r = 0; r < 8; ++r)
                bf[ks][c][r] = smem[(ks * 32 + hi8 + r) * 128 + col];
        }
    }
    __syncthreads();

    const float4* a4 = reinterpret_cast<const float4*>(f + (size_t)rowbase * K);
    for (int n = tid; n < ROWS * K / 8; n += 256) {
        const int row   = n / (K / 8);
        const int k8    = (n % (K / 8)) * 8;
        const int base4 = (row * K + k8) >> 2;
        const float4 u = a4[base4];
        const float4 v = a4[base4 + 1];
        short8_t s = { (short)f2bf(u.x), (short)f2bf(u.y), (short)f2bf(u.z), (short)f2bf(u.w),
                       (short)f2bf(v.x), (short)f2bf(v.y), (short)f2bf(v.z), (short)f2bf(v.w) };
        const int idx = (row * K + k8) ^ ((row & 7) << 3);
        *reinterpret_cast<short8_t*>(&smem[idx]) = s;
    }
    __syncthreads();

    f32x4 acc[MF][2];
    #pragma unroll
    for (int m = 0; m < MF; ++m) {
        #pragma unroll
        for (int c = 0; c < 2; ++c) acc[m][c] = (f32x4){0.f, 0.f, 0.f, 0.f};
    }

    const int axor = (lane & 7) << 3;
    #pragma unroll
    for (int ks = 0; ks < KS; ++ks) {
        #pragma unroll
        for (int m = 0; m < MF; ++m) {
            const int aidx = ((m * 16 + lo16) * K + ks * 32 + hi8) ^ axor;
            const short8_t af = *reinterpret_cast<const short8_t*>(&smem[aidx]);
            acc[m][0] = __builtin_amdgcn_mfma_f32_16x16x32_bf16(af, bf[ks][0], acc[m][0], 0, 0, 0);
            acc[m][1] = __builtin_amdgcn_mfma_f32_16x16x32_bf16(af, bf[ks][1], acc[m][1], 0, 0, 0);
        }
    }

    #pragma unroll
    for (int c = 0; c < 2; ++c) {
        const int col = wv * 32 + c * 16 + lo16;
        const float bb = bias[col];
        #pragma unroll
        for (int m = 0; m < MF; ++m) {
            #pragma unroll
            for (int r = 0; r < 4; ++r) {
                const int row = rowbase + m * 16 + (lane >> 4) * 4 + r;
                outf[(size_t)row * 128 + col] = acc[m][c][r] + bb;
            }
        }
    }
}

// ---------------------------------------------------------------------------
// Insert macros (proven R3/R5/R7).
// ---------------------------------------------------------------------------
#define INS3M(d0, d1, d2, i0, i1, i2, dd, ss)                               \
    {                                                                       \
        const bool c0 = (dd) < d0, c1 = (dd) < d1, c2 = (dd) < d2;          \
        i2 = c1 ? i1 : (c2 ? (ss) : i2);                                    \
        i1 = c0 ? i0 : (c1 ? (ss) : i1);                                    \
        i0 = c0 ? (ss) : i0;                                                \
        d2 = fminf(fmaxf((dd), d1), d2);                                    \
        d1 = fminf(fmaxf((dd), d0), d1);                                    \
        d0 = fminf(d0, (dd));                                               \
    }

#define INS3L(d0, d1, d2, i0, i1, i2, dd, ss)                               \
    {                                                                       \
        const bool c0 = ((dd) < d0) | (((dd) == d0) & ((ss) < i0));         \
        const bool c1 = ((dd) < d1) | (((dd) == d1) & ((ss) < i1));         \
        const bool c2 = ((dd) < d2) | (((dd) == d2) & ((ss) < i2));         \
        i2 = c1 ? i1 : (c2 ? (ss) : i2);                                    \
        i1 = c0 ? i0 : (c1 ? (ss) : i1);                                    \
        i0 = c0 ? (ss) : i0;                                                \
        d2 = c1 ? d1 : (c2 ? (dd) : d2);                                    \
        d1 = c0 ? d0 : (c1 ? (dd) : d1);                                    \
        d0 = c0 ? (dd) : d0;                                                \
    }

// ---------------------------------------------------------------------------
// PROBE C: k_nn3 — R7's PASSING wave-parallel selection, verbatim through the
// butterfly; the ONLY change is the epilogue: sp==0 lanes write idx/weight
// triples to GLOBAL qidx/qw (instead of LDS si/sw + in-kernel gather).
// Single variable vs passing R7: the global round-trip + separate gather.
// ---------------------------------------------------------------------------
__global__ __launch_bounds__(256) void k_nn3(const float4* __restrict__ dxyzp,
                                             const float4* __restrict__ oxyzp,
                                             int*          __restrict__ qidx,
                                             float*        __restrict__ qw) {
    __shared__ float4 sx[16 * 65];

    const int b     = blockIdx.x >> 10;           // 1024 blocks per batch
    const int qbase = (blockIdx.x & 1023) * 16;

    const int lane = threadIdx.x & 63;
    const int wave = threadIdx.x >> 6;
    const int sp   = lane & 15;
    const int qs   = lane >> 4;
    const int slot = wave * 4 + qs;               // 0..15 within block

    const float4 o = oxyzp[(size_t)b * N + qbase + slot];
    const float sumo = __fadd_rn(__fadd_rn(__fmul_rn(o.x, o.x), __fmul_rn(o.y, o.y)),
                                 __fmul_rn(o.z, o.z));

    float a0 = FLT_MAX, a1 = FLT_MAX, a2 = FLT_MAX;
    int   ai0 = 0, ai1 = 0, ai2 = 0;

    const float4* dpb = dxyzp + (size_t)b * S;

    for (int c = 0; c < 4; ++c) {
        if (c > 0) __syncthreads();
        const float4* dpc = dpb + c * 1024;
        for (int j = threadIdx.x; j < 1024; j += 256) {
            float4 v = dpc[j];
            const float ss = __fadd_rn(__fadd_rn(__fmul_rn(v.x, v.x), __fmul_rn(v.y, v.y)),
                                       __fmul_rn(v.z, v.z));
            float4 w;
            w.x = v.x + v.x;
            w.y = v.y + v.y;
            w.z = v.z + v.z;
            w.w = ss;
            sx[(j >> 6) * 65 + (j & 63)] = w;
        }
        __syncthreads();

        const float4* base = &sx[sp * 65];
        const int g0 = c * 1024 + sp * 64;

        #pragma unroll 4
        for (int i = 0; i < 64; ++i) {
            const float4 q = base[i];
            const float dot2 = __fadd_rn(__fadd_rn(__fmul_rn(q.x, o.x), __fmul_rn(q.y, o.y)),
                                         __fmul_rn(q.z, o.z));
            const float dd = __fsub_rn(__fadd_rn(sumo, q.w), dot2);
            INS3M(a0, a1, a2, ai0, ai1, ai2, dd, g0 + i);
        }
    }

    #pragma unroll
    for (int m = 1; m <= 8; m <<= 1) {
        const float nd0 = __shfl_xor(a0, m, 64);
        const float nd1 = __shfl_xor(a1, m, 64);
        const float nd2 = __shfl_xor(a2, m, 64);
        const int   ni0 = __shfl_xor(ai0, m, 64);
        const int   ni1 = __shfl_xor(ai1, m, 64);
        const int   ni2 = __shfl_xor(ai2, m, 64);
        INS3L(a0, a1, a2, ai0, ai1, ai2, nd0, ni0);
        INS3L(a0, a1, a2, ai0, ai1, ai2, nd1, ni1);
        INS3L(a0, a1, a2, ai0, ai1, ai2, nd2, ni2);
    }

    if (sp == 0) {
        const float r0 = 1.0f / (a0 + 1e-8f);
        const float r1 = 1.0f / (a1 + 1e-8f);
        const float r2 = 1.0f / (a2 + 1e-8f);
        const float rs = __fadd_rn(__fadd_rn(r0, r1), r2);
        const int row = b * N + qbase + slot;     // global query row
        qidx[row * 3 + 0] = ai0;
        qidx[row * 3 + 1] = ai1;
        qidx[row * 3 + 2] = ai2;
        qw[row * 3 + 0] = r0 / rs;
        qw[row * 3 + 1] = r1 / rs;
        qw[row * 3 + 2] = r2 / rs;
    }
}

// ---------------------------------------------------------------------------
// k_gather (R10-verbatim).
// ---------------------------------------------------------------------------
__global__ __launch_bounds__(256) void k_gather(const float* __restrict__ downf,
                                                const int*   __restrict__ qidx,
                                                const float* __restrict__ qw,
                                                float*       __restrict__ out) {
    const int ch = threadIdx.x & 127;
    const int hf = threadIdx.x >> 7;
    const int rowbase = blockIdx.x * 16;

    for (int pp = hf; pp < 16; pp += 2) {
        const int row = rowbase + pp;
        const int b = row >> 14;
        const float* df = downf + (size_t)b * S * OUTC;
        const int   j0 = qidx[row * 3 + 0];
        const int   j1 = qidx[row * 3 + 1];
        const int   j2 = qidx[row * 3 + 2];
        const float w0 = qw[row * 3 + 0];
        const float w1 = qw[row * 3 + 1];
        const float w2 = qw[row * 3 + 2];
        const float g = __fadd_rn(
            __fadd_rn(__fmul_rn(w0, df[(size_t)j0 * OUTC + ch]),
                      __fmul_rn(w1, df[(size_t)j1 * OUTC + ch])),
            __fmul_rn(w2, df[(size_t)j2 * OUTC + ch]));
        out[(size_t)row * OUTC + ch] += g;
    }
}

// ---------------------------------------------------------------------------
// Fallback: R7's fully-fused k_interp (passing), if ws were ever too small.
// ---------------------------------------------------------------------------
__global__ __launch_bounds__(256) void k_interp(const float4* __restrict__ dxyzp,
                                                const float4* __restrict__ oxyzp,
                                                const float*  __restrict__ downf,
                                                float*        __restrict__ out) {
    __shared__ float4 sx[16 * 65];
    __shared__ int    si[16 * 3];
    __shared__ float  sw[16 * 3];

    const int b     = blockIdx.x >> 10;
    const int qbase = (blockIdx.x & 1023) * 16;

    const int lane = threadIdx.x & 63;
    const int wave = threadIdx.x >> 6;
    const int sp   = lane & 15;
    const int qs   = lane >> 4;
    const int slot = wave * 4 + qs;

    const float4 o = oxyzp[(size_t)b * N + qbase + slot];
    const float sumo = __fadd_rn(__fadd_rn(__fmul_rn(o.x, o.x), __fmul_rn(o.y, o.y)),
                                 __fmul_rn(o.z, o.z));

    float a0 = FLT_MAX, a1 = FLT_MAX, a2 = FLT_MAX;
    int   ai0 = 0, ai1 = 0, ai2 = 0;

    const float4* dpb = dxyzp + (size_t)b * S;

    for (int c = 0; c < 4; ++c) {
        if (c > 0) __syncthreads();
        const float4* dpc = dpb + c * 1024;
        for (int j = threadIdx.x; j < 1024; j += 256) {
            float4 v = dpc[j];
            const float ss = __fadd_rn(__fadd_rn(__fmul_rn(v.x, v.x), __fmul_rn(v.y, v.y)),
                                       __fmul_rn(v.z, v.z));
            float4 w;
            w.x = v.x + v.x;
            w.y = v.y + v.y;
            w.z = v.z + v.z;
            w.w = ss;
            sx[(j >> 6) * 65 + (j & 63)] = w;
        }
        __syncthreads();

        const float4* base = &sx[sp * 65];
        const int g0 = c * 1024 + sp * 64;

        #pragma unroll 4
        for (int i = 0; i < 64; ++i) {
            const float4 q = base[i];
            const float dot2 = __fadd_rn(__fadd_rn(__fmul_rn(q.x, o.x), __fmul_rn(q.y, o.y)),
                                         __fmul_rn(q.z, o.z));
            const float dd = __fsub_rn(__fadd_rn(sumo, q.w), dot2);
            INS3M(a0, a1, a2, ai0, ai1, ai2, dd, g0 + i);
        }
    }

    #pragma unroll
    for (int m = 1; m <= 8; m <<= 1) {
        const float nd0 = __shfl_xor(a0, m, 64);
        const float nd1 = __shfl_xor(a1, m, 64);
        const float nd2 = __shfl_xor(a2, m, 64);
        const int   ni0 = __shfl_xor(ai0, m, 64);
        const int   ni1 = __shfl_xor(ai1, m, 64);
        const int   ni2 = __shfl_xor(ai2, m, 64);
        INS3L(a0, a1, a2, ai0, ai1, ai2, nd0, ni0);
        INS3L(a0, a1, a2, ai0, ai1, ai2, nd1, ni1);
        INS3L(a0, a1, a2, ai0, ai1, ai2, nd2, ni2);
    }

    if (sp == 0) {
        const float r0 = 1.0f / (a0 + 1e-8f);
        const float r1 = 1.0f / (a1 + 1e-8f);
        const float r2 = 1.0f / (a2 + 1e-8f);
        const float rs = __fadd_rn(__fadd_rn(r0, r1), r2);
        si[slot * 3 + 0] = ai0;
        si[slot * 3 + 1] = ai1;
        si[slot * 3 + 2] = ai2;
        sw[slot * 3 + 0] = r0 / rs;
        sw[slot * 3 + 1] = r1 / rs;
        sw[slot * 3 + 2] = r2 / rs;
    }
    __syncthreads();

    const int ch = threadIdx.x & 127;
    const int hf = threadIdx.x >> 7;
    const float* df = downf + (size_t)b * S * OUTC;
    float* ob = out + ((size_t)b * N + qbase) * OUTC;

    for (int pp = hf; pp < 16; pp += 2) {
        const int   j0 = si[pp * 3 + 0];
        const int   j1 = si[pp * 3 + 1];
        const int   j2 = si[pp * 3 + 2];
        const float w0 = sw[pp * 3 + 0];
        const float w1 = sw[pp * 3 + 1];
        const float w2 = sw[pp * 3 + 2];
        const float g = __fadd_rn(
            __fadd_rn(__fmul_rn(w0, df[(size_t)j0 * OUTC + ch]),
                      __fmul_rn(w1, df[(size_t)j1 * OUTC + ch])),
            __fmul_rn(w2, df[(size_t)j2 * OUTC + ch]));
        ob[(size_t)pp * OUTC + ch] += g;
    }
}

// ---------------------------------------------------------------------------

extern "C" void kernel_launch(void* const* d_in, const int* in_sizes, int n_in,
                              void* d_out, int out_size, void* d_ws, size_t ws_size,
                              hipStream_t stream) {
    const float* dxyzp = (const float*)d_in[0];   // (B,S,4)
    const float* dfeat = (const float*)d_in[1];   // (B,S,256)
    const float* oxyzp = (const float*)d_in[2];   // (B,N,4)
    const float* ofeat = (const float*)d_in[3];   // (B,N,128)
    const float* W1    = (const float*)d_in[4];   // (256,128)
    const float* b1    = (const float*)d_in[5];   // (128)
    const float* W2    = (const float*)d_in[6];   // (128,128)
    const float* b2    = (const float*)d_in[7];   // (128)

    float* out   = (float*)d_out;                 // (B,N,128)
    char*  ws    = (char*)d_ws;
    float* downf = (float*)(ws + OFF_DOWNF);      // (B,S,128)

    // down_f / ori_f GEMMs (frozen, passing since R6)
    k_mfma<INC, 32><<<(B * S) / 32, 256, 0, stream>>>(dfeat, W1, b1, downf);
    k_mfma<OUTC, 64><<<(B * N) / 64, 256, 0, stream>>>(ofeat, W2, b2, out);

    if (ws_size >= WS_NEED) {
        int*   qidx = (int*)  (ws + OFF_QIDX);
        float* qw   = (float*)(ws + OFF_QW);

        // PROBE C: R7-proven selection -> global qidx/qw -> separate gather.
        k_nn3   <<<B * (N / 16), 256, 0, stream>>>(
            (const float4*)dxyzp, (const float4*)oxyzp, qidx, qw);
        k_gather<<<2048, 256, 0, stream>>>(downf, qidx, qw, out);
    } else {
        k_interp<<<B * (N / 16), 256, 0, stream>>>(
            (const float4*)dxyzp, (const float4*)oxyzp, downf, out);
    }
}

// Round 12
// 108.839 us; speedup vs baseline: 1.1161x; 1.1161x over previous
//
#include <hip/hip_runtime.h>
#include <hip/hip_bf16.h>
#include <float.h>

// Problem constants
constexpr int B   = 2;
constexpr int N   = 16384;
constexpr int S   = 4096;
constexpr int INC = 256;
constexpr int OUTC = 128;

// Workspace: only down_f scratch (4 MB).
constexpr size_t OFF_DOWNF = 0;

typedef short short4_t __attribute__((ext_vector_type(4)));
typedef short short8_t __attribute__((ext_vector_type(8)));
typedef float f32x4    __attribute__((ext_vector_type(4)));

__device__ __forceinline__ unsigned short f2bf(float f) {
    unsigned u = __builtin_bit_cast(unsigned, f);
    u += 0x7fffu + ((u >> 16) & 1u);          // round-to-nearest-even
    return (unsigned short)(u >> 16);
}

// ---------------------------------------------------------------------------
// MFMA GEMM (unchanged, passing since R6) — used for down_f only.
// ---------------------------------------------------------------------------
template <int K, int ROWS>
__global__ __launch_bounds__(256) void k_mfma(const float* __restrict__ f,
                                              const float* __restrict__ W,
                                              const float* __restrict__ bias,
                                              float* __restrict__ outf) {
    constexpr int MF = ROWS / 16;
    constexpr int KS = K / 32;
    __shared__ __align__(16) short smem[K * 128];

    const int tid  = threadIdx.x;
    const int lane = tid & 63;
    const int wv   = tid >> 6;
    const int rowbase = blockIdx.x * ROWS;
    const int lo16 = lane & 15;
    const int hi8  = (lane >> 4) * 8;

    const float4* w4 = reinterpret_cast<const float4*>(W);
    for (int n = tid; n < K * 32; n += 256) {
        const float4 u = w4[n];
        short4_t s = { (short)f2bf(u.x), (short)f2bf(u.y),
                       (short)f2bf(u.z), (short)f2bf(u.w) };
        *reinterpret_cast<short4_t*>(&smem[n * 4]) = s;
    }
    __syncthreads();

    short8_t bf[KS][2];
    #pragma unroll
    for (int ks = 0; ks < KS; ++ks) {
        #pragma unroll
        for (int c = 0; c < 2; ++c) {
            const int col = wv * 32 + c * 16 + lo16;
            #pragma unroll
            for (int r = 0; r < 8; ++r)
                bf[ks][c][r] = smem[(ks * 32 + hi8 + r) * 128 + col];
        }
    }
    __syncthreads();

    const float4* a4 = reinterpret_cast<const float4*>(f + (size_t)rowbase * K);
    for (int n = tid; n < ROWS * K / 8; n += 256) {
        const int row   = n / (K / 8);
        const int k8    = (n % (K / 8)) * 8;
        const int base4 = (row * K + k8) >> 2;
        const float4 u = a4[base4];
        const float4 v = a4[base4 + 1];
        short8_t s = { (short)f2bf(u.x), (short)f2bf(u.y), (short)f2bf(u.z), (short)f2bf(u.w),
                       (short)f2bf(v.x), (short)f2bf(v.y), (short)f2bf(v.z), (short)f2bf(v.w) };
        const int idx = (row * K + k8) ^ ((row & 7) << 3);
        *reinterpret_cast<short8_t*>(&smem[idx]) = s;
    }
    __syncthreads();

    f32x4 acc[MF][2];
    #pragma unroll
    for (int m = 0; m < MF; ++m) {
        #pragma unroll
        for (int c = 0; c < 2; ++c) acc[m][c] = (f32x4){0.f, 0.f, 0.f, 0.f};
    }

    const int axor = (lane & 7) << 3;
    #pragma unroll
    for (int ks = 0; ks < KS; ++ks) {
        #pragma unroll
        for (int m = 0; m < MF; ++m) {
            const int aidx = ((m * 16 + lo16) * K + ks * 32 + hi8) ^ axor;
            const short8_t af = *reinterpret_cast<const short8_t*>(&smem[aidx]);
            acc[m][0] = __builtin_amdgcn_mfma_f32_16x16x32_bf16(af, bf[ks][0], acc[m][0], 0, 0, 0);
            acc[m][1] = __builtin_amdgcn_mfma_f32_16x16x32_bf16(af, bf[ks][1], acc[m][1], 0, 0, 0);
        }
    }

    #pragma unroll
    for (int c = 0; c < 2; ++c) {
        const int col = wv * 32 + c * 16 + lo16;
        const float bb = bias[col];
        #pragma unroll
        for (int m = 0; m < MF; ++m) {
            #pragma unroll
            for (int r = 0; r < 4; ++r) {
                const int row = rowbase + m * 16 + (lane >> 4) * 4 + r;
                outf[(size_t)row * 128 + col] = acc[m][c][r] + bb;
            }
        }
    }
}

// ---------------------------------------------------------------------------
// Insert macros (proven R3/R5/R7/R11).
// ---------------------------------------------------------------------------
#define INS3M(d0, d1, d2, i0, i1, i2, dd, ss)                               \
    {                                                                       \
        const bool c0 = (dd) < d0, c1 = (dd) < d1, c2 = (dd) < d2;          \
        i2 = c1 ? i1 : (c2 ? (ss) : i2);                                    \
        i1 = c0 ? i0 : (c1 ? (ss) : i1);                                    \
        i0 = c0 ? (ss) : i0;                                                \
        d2 = fminf(fmaxf((dd), d1), d2);                                    \
        d1 = fminf(fmaxf((dd), d0), d1);                                    \
        d0 = fminf(d0, (dd));                                               \
    }

#define INS3L(d0, d1, d2, i0, i1, i2, dd, ss)                               \
    {                                                                       \
        const bool c0 = ((dd) < d0) | (((dd) == d0) & ((ss) < i0));         \
        const bool c1 = ((dd) < d1) | (((dd) == d1) & ((ss) < i1));         \
        const bool c2 = ((dd) < d2) | (((dd) == d2) & ((ss) < i2));         \
        i2 = c1 ? i1 : (c2 ? (ss) : i2);                                    \
        i1 = c0 ? i0 : (c1 ? (ss) : i1);                                    \
        i0 = c0 ? (ss) : i0;                                                \
        d2 = c1 ? d1 : (c2 ? (dd) : d2);                                    \
        d1 = c0 ? d0 : (c1 ? (dd) : d1);                                    \
        d0 = c0 ? (dd) : d0;                                                \
    }

// ---------------------------------------------------------------------------
// k_fused: per block = 16 query rows.
//   Phase 1 (new glue, components R6-proven): ori_f 16x128 GEMM via MFMA
//     (W2 + A-tile staged bf16 in LDS, acc kept in registers).
//   Phase 2 (R7/R11-verbatim): wave-parallel 3-NN over 4 LDS chunks of 1024
//     candidates; INS3M ascending streams + lexicographic butterfly.
//   Phase 3: per-acc-element gather of down_f + (acc + bias) + interp write.
// LDS: [0,32768) W2 bf16 -> reused for sx (16*65 float4 = 16640 B);
//      [32768,36864) A-tile bf16; [36864,37248) si/sw.
// ---------------------------------------------------------------------------
__global__ __launch_bounds__(256) void k_fused(const float4* __restrict__ dxyzp,
                                               const float4* __restrict__ oxyzp,
                                               const float*  __restrict__ ofeat,
                                               const float*  __restrict__ W2,
                                               const float*  __restrict__ b2,
                                               const float*  __restrict__ downf,
                                               float*        __restrict__ out) {
    __shared__ __align__(16) char lds[37248];
    short*  sW = reinterpret_cast<short*>(lds);             // [128*128] bf16
    short*  sA = reinterpret_cast<short*>(lds + 32768);     // [16*128]  bf16
    float4* sx = reinterpret_cast<float4*>(lds);            // [16*65]   (reuse)
    int*    si = reinterpret_cast<int*>(lds + 36864);       // [48]
    float*  sw = reinterpret_cast<float*>(lds + 37056);     // [48]

    const int tid  = threadIdx.x;
    const int lane = tid & 63;
    const int wv   = tid >> 6;
    const int b     = blockIdx.x >> 10;           // 1024 blocks per batch
    const int qbase = (blockIdx.x & 1023) * 16;
    const int lo16 = lane & 15;
    const int hi8  = (lane >> 4) * 8;

    // ---- Phase 1a: stage W2 (bf16, row-major [128][128]) ----
    const float4* w4 = reinterpret_cast<const float4*>(W2);
    for (int n = tid; n < 128 * 32; n += 256) {   // 4096 float4
        const float4 u = w4[n];
        short4_t s = { (short)f2bf(u.x), (short)f2bf(u.y),
                       (short)f2bf(u.z), (short)f2bf(u.w) };
        *reinterpret_cast<short4_t*>(&sW[n * 4]) = s;
    }
    // ---- Phase 1b: stage A-tile (16 rows of ofeat, bf16, XOR-swizzled) ----
    {
        const float4* a4 = reinterpret_cast<const float4*>(
            ofeat + (size_t)(b * N + qbase) * 128);
        const int n    = tid;                     // 256 jobs, 1 per thread
        const int row  = n >> 4;                  // 0..15
        const int k8   = (n & 15) * 8;
        const int base4 = (row * 128 + k8) >> 2;
        const float4 u = a4[base4];
        const float4 v = a4[base4 + 1];
        short8_t s = { (short)f2bf(u.x), (short)f2bf(u.y), (short)f2bf(u.z), (short)f2bf(u.w),
                       (short)f2bf(v.x), (short)f2bf(v.y), (short)f2bf(v.z), (short)f2bf(v.w) };
        const int idx = (row * 128 + k8) ^ ((row & 7) << 3);
        *reinterpret_cast<short8_t*>(&sA[idx]) = s;
    }
    __syncthreads();

    // ---- B fragments (registers) ----
    short8_t bfr[4][2];
    #pragma unroll
    for (int ks = 0; ks < 4; ++ks) {
        #pragma unroll
        for (int c = 0; c < 2; ++c) {
            const int col = wv * 32 + c * 16 + lo16;
            #pragma unroll
            for (int r = 0; r < 8; ++r)
                bfr[ks][c][r] = sW[(ks * 32 + hi8 + r) * 128 + col];
        }
    }

    // ---- MFMA: acc = ofeat_tile @ W2 (MF=1, KS=4) ----
    f32x4 acc[2] = { (f32x4){0.f,0.f,0.f,0.f}, (f32x4){0.f,0.f,0.f,0.f} };
    const int axor = (lane & 7) << 3;
    #pragma unroll
    for (int ks = 0; ks < 4; ++ks) {
        const int aidx = (lo16 * 128 + ks * 32 + hi8) ^ axor;
        const short8_t af = *reinterpret_cast<const short8_t*>(&sA[aidx]);
        acc[0] = __builtin_amdgcn_mfma_f32_16x16x32_bf16(af, bfr[ks][0], acc[0], 0, 0, 0);
        acc[1] = __builtin_amdgcn_mfma_f32_16x16x32_bf16(af, bfr[ks][1], acc[1], 0, 0, 0);
    }
    __syncthreads();                              // W2/A regions now dead

    // ---- Phase 2: 3-NN search (R7/R11-verbatim) ----
    const int sp   = lane & 15;
    const int qs   = lane >> 4;
    const int slot = wv * 4 + qs;                 // 0..15 within block

    const float4 o = oxyzp[(size_t)b * N + qbase + slot];
    const float sumo = __fadd_rn(__fadd_rn(__fmul_rn(o.x, o.x), __fmul_rn(o.y, o.y)),
                                 __fmul_rn(o.z, o.z));

    float a0 = FLT_MAX, a1 = FLT_MAX, a2 = FLT_MAX;
    int   ai0 = 0, ai1 = 0, ai2 = 0;

    const float4* dpb = dxyzp + (size_t)b * S;

    for (int c = 0; c < 4; ++c) {
        if (c > 0) __syncthreads();
        const float4* dpc = dpb + c * 1024;
        for (int j = tid; j < 1024; j += 256) {
            float4 v = dpc[j];
            const float ss = __fadd_rn(__fadd_rn(__fmul_rn(v.x, v.x), __fmul_rn(v.y, v.y)),
                                       __fmul_rn(v.z, v.z));
            float4 w;
            w.x = v.x + v.x;
            w.y = v.y + v.y;
            w.z = v.z + v.z;
            w.w = ss;
            sx[(j >> 6) * 65 + (j & 63)] = w;
        }
        __syncthreads();

        const float4* base = &sx[sp * 65];
        const int g0 = c * 1024 + sp * 64;

        #pragma unroll 4
        for (int i = 0; i < 64; ++i) {
            const float4 q = base[i];
            const float dot2 = __fadd_rn(__fadd_rn(__fmul_rn(q.x, o.x), __fmul_rn(q.y, o.y)),
                                         __fmul_rn(q.z, o.z));
            const float dd = __fsub_rn(__fadd_rn(sumo, q.w), dot2);
            INS3M(a0, a1, a2, ai0, ai1, ai2, dd, g0 + i);
        }
    }

    #pragma unroll
    for (int m = 1; m <= 8; m <<= 1) {
        const float nd0 = __shfl_xor(a0, m, 64);
        const float nd1 = __shfl_xor(a1, m, 64);
        const float nd2 = __shfl_xor(a2, m, 64);
        const int   ni0 = __shfl_xor(ai0, m, 64);
        const int   ni1 = __shfl_xor(ai1, m, 64);
        const int   ni2 = __shfl_xor(ai2, m, 64);
        INS3L(a0, a1, a2, ai0, ai1, ai2, nd0, ni0);
        INS3L(a0, a1, a2, ai0, ai1, ai2, nd1, ni1);
        INS3L(a0, a1, a2, ai0, ai1, ai2, nd2, ni2);
    }

    if (sp == 0) {
        const float r0 = 1.0f / (a0 + 1e-8f);
        const float r1 = 1.0f / (a1 + 1e-8f);
        const float r2 = 1.0f / (a2 + 1e-8f);
        const float rs = __fadd_rn(__fadd_rn(r0, r1), r2);
        si[slot * 3 + 0] = ai0;
        si[slot * 3 + 1] = ai1;
        si[slot * 3 + 2] = ai2;
        sw[slot * 3 + 0] = r0 / rs;
        sw[slot * 3 + 1] = r1 / rs;
        sw[slot * 3 + 2] = r2 / rs;
    }
    __syncthreads();

    // ---- Phase 3: gather + epilogue, per acc element ----
    const float* df = downf + (size_t)b * S * OUTC;
    float* ob = out + (size_t)(b * N + qbase) * OUTC;

    #pragma unroll
    for (int c = 0; c < 2; ++c) {
        const int col = wv * 32 + c * 16 + lo16;
        const float bb = b2[col];
        #pragma unroll
        for (int r = 0; r < 4; ++r) {
            const int row16 = (lane >> 4) * 4 + r;
            const int   j0 = si[row16 * 3 + 0];
            const int   j1 = si[row16 * 3 + 1];
            const int   j2 = si[row16 * 3 + 2];
            const float w0 = sw[row16 * 3 + 0];
            const float w1 = sw[row16 * 3 + 1];
            const float w2 = sw[row16 * 3 + 2];
            const float g = __fadd_rn(
                __fadd_rn(__fmul_rn(w0, df[(size_t)j0 * OUTC + col]),
                          __fmul_rn(w1, df[(size_t)j1 * OUTC + col])),
                __fmul_rn(w2, df[(size_t)j2 * OUTC + col]));
            ob[(size_t)row16 * OUTC + col] = (acc[c][r] + bb) + g;
        }
    }
}

// ---------------------------------------------------------------------------

extern "C" void kernel_launch(void* const* d_in, const int* in_sizes, int n_in,
                              void* d_out, int out_size, void* d_ws, size_t ws_size,
                              hipStream_t stream) {
    const float* dxyzp = (const float*)d_in[0];   // (B,S,4)
    const float* dfeat = (const float*)d_in[1];   // (B,S,256)
    const float* oxyzp = (const float*)d_in[2];   // (B,N,4)
    const float* ofeat = (const float*)d_in[3];   // (B,N,128)
    const float* W1    = (const float*)d_in[4];   // (256,128)
    const float* b1    = (const float*)d_in[5];   // (128)
    const float* W2    = (const float*)d_in[6];   // (128,128)
    const float* b2    = (const float*)d_in[7];   // (128)

    float* out   = (float*)d_out;                 // (B,N,128)
    float* downf = (float*)((char*)d_ws + OFF_DOWNF);   // (B,S,128)

    // down_f = down_features @ W1 + b1 -> workspace (MFMA bf16, frozen)
    k_mfma<INC, 32><<<(B * S) / 32, 256, 0, stream>>>(dfeat, W1, b1, downf);

    // Fused: ori_f GEMM + 3-NN search + interpolation -> out
    k_fused<<<B * (N / 16), 256, 0, stream>>>(
        (const float4*)dxyzp, (const float4*)oxyzp, ofeat, W2, b2, downf, out);
}